// Round 1
// baseline (1510.035 us; speedup 1.0000x reference)
//
#include <hip/hip_runtime.h>
#include <hip/hip_bf16.h>
#include <cstddef>

typedef unsigned short u16;
typedef unsigned int u32;
typedef short short8 __attribute__((ext_vector_type(8)));
typedef float floatx4 __attribute__((ext_vector_type(4)));

#define T_STEPS 500
#define BATCH 64
#define INDIM 440
#define INPAD 448
#define HID 1024
#define OUTDIM 1944
#define OUTPAD 2048
#define MROWS 32000  // T*B
#define INV_SQRT_BN 0.9999950000374997f  // 1/sqrt(1+1e-5)

__device__ __forceinline__ u16 f2bf_rne(float f) {
  u32 u = __float_as_uint(f);
  u32 r = (u + 0x7FFFu + ((u >> 16) & 1u)) >> 16;
  return (u16)r;
}
__device__ __forceinline__ u16 f2bf_exact(float f) {
  // exact for small integers (mantissa fits in 7 bits)
  return (u16)(__float_as_uint(f) >> 16);
}
__device__ __forceinline__ void g2lds16(const void* g, void* l) {
  __builtin_amdgcn_global_load_lds(
      (const __attribute__((address_space(1))) u32*)g,
      (__attribute__((address_space(3))) u32*)l, 16, 0, 0);
}

// ---------------- input FSQ scan: xs [T,B,440] -> spikes bf16 [T*B, 448] ----
__global__ __launch_bounds__(256) void input_fsq_k(const float* __restrict__ xs,
                                                   u16* __restrict__ sp0) {
  int tid = blockIdx.x * 256 + threadIdx.x;  // 64*448
  int b = tid / INPAD;
  int i = tid - b * INPAD;
  bool act = (i < INDIM);
  const float* src = xs + (size_t)b * INDIM + i;
  u16* dst = sp0 + (size_t)b * INPAD + i;
  float vmem = 0.f;
#pragma unroll 4
  for (int t = 0; t < T_STEPS; ++t) {
    float x = act ? src[(size_t)t * (BATCH * INDIM)] : 0.f;
    vmem += x;
    float q = fminf(fmaxf(rintf(vmem), 0.f), 7.f);
    vmem -= q;
    dst[(size_t)t * (BATCH * INPAD)] = f2bf_exact(q);
  }
}

// ---------------- LIF scan: ws fp32 [T*B, 1024] -> spikes bf16 ----
__global__ __launch_bounds__(256) void lif_k(const float* __restrict__ ws,
                                             const float* __restrict__ taus,
                                             u16* __restrict__ sp) {
  int tid = blockIdx.x * 256 + threadIdx.x;  // 65536 = B*HID
  float tau = taus[tid & (HID - 1)];
  const float* src = ws + tid;
  u16* dst = sp + tid;
  float syn = 0.f, vmem = 0.f;
#pragma unroll 4
  for (int t = 0; t < T_STEPS; ++t) {
    float w = src[(size_t)t * (BATCH * HID)];
    syn = fmaf(tau, syn, w);
    vmem += syn;
    float q = fminf(fmaxf(rintf(vmem), 0.f), 7.f);
    vmem -= q;
    dst[(size_t)t * (BATCH * HID)] = f2bf_exact(q);
  }
}

// ---------------- weight prep: fold BN gamma, split to bf16 hi/lo ----
__global__ __launch_bounds__(256) void prep_w0_k(const float* __restrict__ W0,
                                                 const float* __restrict__ g,
                                                 u16* __restrict__ hi, u16* __restrict__ lo) {
  int idx = blockIdx.x * 256 + threadIdx.x;  // 1024*448
  int h = idx / INPAD, k = idx - h * INPAD;
  float w = 0.f;
  if (k < INDIM) w = W0[(size_t)h * INDIM + k] * g[h] * INV_SQRT_BN;
  u16 hb = f2bf_rne(w);
  float hf = __uint_as_float((u32)hb << 16);
  hi[idx] = hb;
  lo[idx] = f2bf_rne(w - hf);
}
__global__ __launch_bounds__(256) void prep_ws_k(const float* __restrict__ Ws,
                                                 const float* __restrict__ g,
                                                 u16* __restrict__ hi, u16* __restrict__ lo) {
  int idx = blockIdx.x * 256 + threadIdx.x;  // 3*1024*1024
  int l = idx >> 20;
  int h = (idx >> 10) & (HID - 1);
  float w = Ws[idx] * g[(l + 1) * HID + h] * INV_SQRT_BN;
  u16 hb = f2bf_rne(w);
  float hf = __uint_as_float((u32)hb << 16);
  hi[idx] = hb;
  lo[idx] = f2bf_rne(w - hf);
}
__global__ __launch_bounds__(256) void prep_wf_k(const float* __restrict__ Wf,
                                                 const float* __restrict__ g,
                                                 u16* __restrict__ hi) {
  int idx = blockIdx.x * 256 + threadIdx.x;  // 2048*1024
  int o = idx >> 10, k = idx & (HID - 1);
  float w = 0.f;
  if (o < OUTDIM) w = Wf[(size_t)o * HID + k] * g[o] * INV_SQRT_BN;
  hi[idx] = f2bf_rne(w);
}

// ---------------- GEMM: C[m,n] = sum_k A[m,k]*(B0+B1)[n,k] + bias[n] ----
// A [M,K] bf16, B [N,K] bf16 (bt layout), C fp32 [M, ldc], store cols < ncols
template <int SPLIT>
__global__ __launch_bounds__(256, 2) void gemm_bt(const u16* __restrict__ A,
                                                  const u16* __restrict__ B0,
                                                  const u16* __restrict__ B1,
                                                  const float* __restrict__ bias,
                                                  float* __restrict__ C,
                                                  int K, int ldc, int ncols) {
  extern __shared__ char smem[];
  u16* As = (u16*)smem;           // [128][64]
  u16* Bs0 = As + 128 * 64;       // [128][64]
  u16* Bs1 = Bs0 + 128 * 64;      // [128][64] (SPLIT only)

  const int tid = threadIdx.x;
  const int m0 = blockIdx.y * 128;
  const int n0 = blockIdx.x * 128;
  const int lane = tid & 63;
  const int wave = tid >> 6;
  const int wm = (wave & 1) * 64;
  const int wn = (wave >> 1) * 64;
  const int lr = lane & 15;
  const int lk = (lane >> 4) * 8;

  floatx4 acc[4][4];
#pragma unroll
  for (int i = 0; i < 4; ++i)
#pragma unroll
    for (int j = 0; j < 4; ++j) {
      floatx4 z = {0.f, 0.f, 0.f, 0.f};
      acc[i][j] = z;
    }

  const int srow = tid >> 3;          // 0..31
  const int scol = (tid & 7) * 8;     // k element offset
  const u16* ga = A + (size_t)(m0 + srow) * K + scol;
  const u16* gb0 = B0 + (size_t)(n0 + srow) * K + scol;
  const u16* gb1 = SPLIT ? B1 + (size_t)(n0 + srow) * K + scol : (const u16*)nullptr;
  const int ldso = tid * 16;

  for (int k0 = 0; k0 < K; k0 += 64) {
#pragma unroll
    for (int it = 0; it < 4; ++it) {
      g2lds16(ga + (size_t)(it * 32) * K + k0, (char*)As + ldso + it * 4096);
      g2lds16(gb0 + (size_t)(it * 32) * K + k0, (char*)Bs0 + ldso + it * 4096);
      if (SPLIT) g2lds16(gb1 + (size_t)(it * 32) * K + k0, (char*)Bs1 + ldso + it * 4096);
    }
    __syncthreads();
#pragma unroll
    for (int kk = 0; kk < 2; ++kk) {
      const int ko = kk * 32 + lk;
      short8 af[4];
#pragma unroll
      for (int i = 0; i < 4; ++i)
        af[i] = *(const short8*)(As + (wm + i * 16 + lr) * 64 + ko);
#pragma unroll
      for (int j = 0; j < 4; ++j) {
        short8 b0 = *(const short8*)(Bs0 + (wn + j * 16 + lr) * 64 + ko);
#pragma unroll
        for (int i = 0; i < 4; ++i)
          acc[i][j] = __builtin_amdgcn_mfma_f32_16x16x32_bf16(af[i], b0, acc[i][j], 0, 0, 0);
        if (SPLIT) {
          short8 b1 = *(const short8*)(Bs1 + (wn + j * 16 + lr) * 64 + ko);
#pragma unroll
          for (int i = 0; i < 4; ++i)
            acc[i][j] = __builtin_amdgcn_mfma_f32_16x16x32_bf16(af[i], b1, acc[i][j], 0, 0, 0);
        }
      }
    }
    __syncthreads();
  }

  const int rq = (lane >> 4) * 4;
#pragma unroll
  for (int j = 0; j < 4; ++j) {
    int n = n0 + wn + j * 16 + lr;
    if (n < ncols) {
      float bv = bias[n];
#pragma unroll
      for (int i = 0; i < 4; ++i) {
        int mb = m0 + wm + i * 16 + rq;
#pragma unroll
        for (int r = 0; r < 4; ++r)
          C[(size_t)(mb + r) * ldc + n] = acc[i][j][r] + bv;
      }
    }
  }
}

// ---------------- in-place log_softmax over rows of 1944 ----
__global__ __launch_bounds__(256) void logsoftmax_k(float* __restrict__ data) {
  __shared__ float red[8];
  float* p = data + (size_t)blockIdx.x * OUTDIM;
  const int t = threadIdx.x;
  float v[8];
  float mx = -1e30f;
#pragma unroll
  for (int j = 0; j < 8; ++j) {
    int c = t + j * 256;
    v[j] = (c < OUTDIM) ? p[c] : -1e30f;
    mx = fmaxf(mx, v[j]);
  }
#pragma unroll
  for (int o = 32; o > 0; o >>= 1) mx = fmaxf(mx, __shfl_down(mx, o));
  if ((t & 63) == 0) red[t >> 6] = mx;
  __syncthreads();
  mx = fmaxf(fmaxf(red[0], red[1]), fmaxf(red[2], red[3]));
  float s = 0.f;
#pragma unroll
  for (int j = 0; j < 8; ++j) {
    int c = t + j * 256;
    if (c < OUTDIM) s += __expf(v[j] - mx);
  }
#pragma unroll
  for (int o = 32; o > 0; o >>= 1) s += __shfl_down(s, o);
  if ((t & 63) == 0) red[4 + (t >> 6)] = s;
  __syncthreads();
  s = (red[4] + red[5]) + (red[6] + red[7]);
  float lse = mx + __logf(s);
#pragma unroll
  for (int j = 0; j < 8; ++j) {
    int c = t + j * 256;
    if (c < OUTDIM) p[c] = v[j] - lse;
  }
}

extern "C" void kernel_launch(void* const* d_in, const int* in_sizes, int n_in,
                              void* d_out, int out_size, void* d_ws, size_t ws_size,
                              hipStream_t stream) {
  const float* xs = (const float*)d_in[0];
  const float* W0 = (const float*)d_in[1];
  const float* Ws = (const float*)d_in[2];
  const float* taus = (const float*)d_in[3];
  const float* bng = (const float*)d_in[4];
  const float* bnb = (const float*)d_in[5];
  const float* Wf = (const float*)d_in[6];
  const float* fg = (const float*)d_in[7];
  const float* fb = (const float*)d_in[8];
  float* out = (float*)d_out;

  char* p = (char*)d_ws;
  u16* sp0 = (u16*)p;  p += (size_t)MROWS * INPAD * 2;    // 28.7 MB
  u16* sp = (u16*)p;   p += (size_t)MROWS * HID * 2;      // 65.5 MB
  float* wsb = (float*)p; p += (size_t)MROWS * HID * 4;   // 131 MB
  u16* W0hi = (u16*)p; p += (size_t)HID * INPAD * 2;
  u16* W0lo = (u16*)p; p += (size_t)HID * INPAD * 2;
  u16* Whi = (u16*)p;  p += (size_t)3 * HID * HID * 2;
  u16* Wlo = (u16*)p;  p += (size_t)3 * HID * HID * 2;
  u16* Wfhi = (u16*)p; p += (size_t)OUTPAD * HID * 2;

  input_fsq_k<<<(BATCH * INPAD) / 256, 256, 0, stream>>>(xs, sp0);
  prep_w0_k<<<(HID * INPAD) / 256, 256, 0, stream>>>(W0, bng, W0hi, W0lo);
  prep_ws_k<<<(3 * HID * HID) / 256, 256, 0, stream>>>(Ws, bng, Whi, Wlo);
  prep_wf_k<<<(OUTPAD * HID) / 256, 256, 0, stream>>>(Wf, fg, Wfhi);

  // layer 0
  gemm_bt<1><<<dim3(HID / 128, MROWS / 128), 256, 48 * 1024, stream>>>(
      sp0, W0hi, W0lo, bnb, wsb, INPAD, HID, HID);
  lif_k<<<(BATCH * HID) / 256, 256, 0, stream>>>(wsb, taus, sp);
  // layers 1..3
  for (int l = 1; l < 4; ++l) {
    gemm_bt<1><<<dim3(HID / 128, MROWS / 128), 256, 48 * 1024, stream>>>(
        sp, Whi + (size_t)(l - 1) * HID * HID, Wlo + (size_t)(l - 1) * HID * HID,
        bnb + l * HID, wsb, HID, HID, HID);
    lif_k<<<(BATCH * HID) / 256, 256, 0, stream>>>(wsb, taus + l * HID, sp);
  }
  // final projection -> d_out (raw logits), then in-place log_softmax
  gemm_bt<0><<<dim3(OUTPAD / 128, MROWS / 128), 256, 32 * 1024, stream>>>(
      sp, Wfhi, (const u16*)nullptr, fb, out, HID, OUTDIM, OUTDIM);
  logsoftmax_k<<<MROWS, 256, 0, stream>>>(out);
}

// Round 2
// 1142.639 us; speedup vs baseline: 1.3215x; 1.3215x over previous
//
#include <hip/hip_runtime.h>
#include <hip/hip_bf16.h>
#include <cstddef>

typedef unsigned short u16;
typedef unsigned int u32;
typedef short short8 __attribute__((ext_vector_type(8)));
typedef float floatx4 __attribute__((ext_vector_type(4)));

#define T_STEPS 500
#define BATCH 64
#define INDIM 440
#define INPAD 448
#define HID 1024
#define OUTDIM 1944
#define OUTPAD 2048
#define MROWS 32000  // T*B
#define INV_SQRT_BN 0.9999950000374997f  // 1/sqrt(1+1e-5)
#define CH 20        // scan chunk: 500 = 25*20

__device__ __forceinline__ u16 f2bf_rne(float f) {
  u32 u = __float_as_uint(f);
  u32 r = (u + 0x7FFFu + ((u >> 16) & 1u)) >> 16;
  return (u16)r;
}
__device__ __forceinline__ u16 f2bf_exact(float f) {
  // exact for small integers (mantissa fits in 8 bits)
  return (u16)(__float_as_uint(f) >> 16);
}
__device__ __forceinline__ void g2lds16(const void* g, void* l) {
  __builtin_amdgcn_global_load_lds(
      (const __attribute__((address_space(1))) u32*)g,
      (__attribute__((address_space(3))) u32*)l, 16, 0, 0);
}

// ---------------- input FSQ scan: xs [T,B,440] -> spikes bf16 [T*B, 448] ----
// Latency-bound scan fix: 20-step register batches, double-buffered so ~20
// loads are in flight while the dependent vmem chain computes.
__global__ __launch_bounds__(256) void input_fsq_k(const float* __restrict__ xs,
                                                   u16* __restrict__ sp0) {
  int tid = blockIdx.x * 256 + threadIdx.x;  // 64*448
  int b = tid / INPAD;
  int i = tid - b * INPAD;
  bool act = (i < INDIM);
  const float* src = xs + (size_t)b * INDIM + (act ? i : (INDIM - 1));
  u16* dst = sp0 + (size_t)b * INPAD + i;
  float fact = act ? 1.f : 0.f;
  const int LS = BATCH * INDIM;   // load stride (elements)
  const int SS = BATCH * INPAD;   // store stride
  float vmem = 0.f;
  float bufA[CH], bufB[CH];
#pragma unroll
  for (int j = 0; j < CH; ++j) bufA[j] = src[(size_t)j * LS];
  for (int it = 0; it < 12; ++it) {
    const int t0 = it * 2 * CH;
#pragma unroll
    for (int j = 0; j < CH; ++j) bufB[j] = src[(size_t)(t0 + CH + j) * LS];
#pragma unroll
    for (int j = 0; j < CH; ++j) {
      vmem += bufA[j] * fact;
      float q = fminf(fmaxf(rintf(vmem), 0.f), 7.f);
      vmem -= q;
      dst[(size_t)(t0 + j) * SS] = f2bf_exact(q);
    }
#pragma unroll
    for (int j = 0; j < CH; ++j) bufA[j] = src[(size_t)(t0 + 2 * CH + j) * LS];
#pragma unroll
    for (int j = 0; j < CH; ++j) {
      vmem += bufB[j] * fact;
      float q = fminf(fmaxf(rintf(vmem), 0.f), 7.f);
      vmem -= q;
      dst[(size_t)(t0 + CH + j) * SS] = f2bf_exact(q);
    }
  }
  const int t0 = 24 * CH;
#pragma unroll
  for (int j = 0; j < CH; ++j) {
    vmem += bufA[j] * fact;
    float q = fminf(fmaxf(rintf(vmem), 0.f), 7.f);
    vmem -= q;
    dst[(size_t)(t0 + j) * SS] = f2bf_exact(q);
  }
}

// ---------------- LIF scan: ws fp32 [T*B, 1024] -> spikes bf16 ----
__global__ __launch_bounds__(256) void lif_k(const float* __restrict__ ws,
                                             const float* __restrict__ taus,
                                             u16* __restrict__ sp) {
  int tid = blockIdx.x * 256 + threadIdx.x;  // 65536 = B*HID
  float tau = taus[tid & (HID - 1)];
  const float* src = ws + tid;
  u16* dst = sp + tid;
  const int S = BATCH * HID;
  float syn = 0.f, vmem = 0.f;
  float bufA[CH], bufB[CH];
#pragma unroll
  for (int j = 0; j < CH; ++j) bufA[j] = src[(size_t)j * S];
  for (int it = 0; it < 12; ++it) {
    const int t0 = it * 2 * CH;
#pragma unroll
    for (int j = 0; j < CH; ++j) bufB[j] = src[(size_t)(t0 + CH + j) * S];
#pragma unroll
    for (int j = 0; j < CH; ++j) {
      syn = fmaf(tau, syn, bufA[j]);
      vmem += syn;
      float q = fminf(fmaxf(rintf(vmem), 0.f), 7.f);
      vmem -= q;
      dst[(size_t)(t0 + j) * S] = f2bf_exact(q);
    }
#pragma unroll
    for (int j = 0; j < CH; ++j) bufA[j] = src[(size_t)(t0 + 2 * CH + j) * S];
#pragma unroll
    for (int j = 0; j < CH; ++j) {
      syn = fmaf(tau, syn, bufB[j]);
      vmem += syn;
      float q = fminf(fmaxf(rintf(vmem), 0.f), 7.f);
      vmem -= q;
      dst[(size_t)(t0 + CH + j) * S] = f2bf_exact(q);
    }
  }
  const int t0 = 24 * CH;
#pragma unroll
  for (int j = 0; j < CH; ++j) {
    syn = fmaf(tau, syn, bufA[j]);
    vmem += syn;
    float q = fminf(fmaxf(rintf(vmem), 0.f), 7.f);
    vmem -= q;
    dst[(size_t)(t0 + j) * S] = f2bf_exact(q);
  }
}

// ---------------- weight prep: fold BN gamma, split to bf16 hi/lo ----
__global__ __launch_bounds__(256) void prep_w0_k(const float* __restrict__ W0,
                                                 const float* __restrict__ g,
                                                 u16* __restrict__ hi, u16* __restrict__ lo) {
  int idx = blockIdx.x * 256 + threadIdx.x;  // 1024*448
  int h = idx / INPAD, k = idx - h * INPAD;
  float w = 0.f;
  if (k < INDIM) w = W0[(size_t)h * INDIM + k] * g[h] * INV_SQRT_BN;
  u16 hb = f2bf_rne(w);
  float hf = __uint_as_float((u32)hb << 16);
  hi[idx] = hb;
  lo[idx] = f2bf_rne(w - hf);
}
__global__ __launch_bounds__(256) void prep_ws_k(const float* __restrict__ Ws,
                                                 const float* __restrict__ g,
                                                 u16* __restrict__ hi, u16* __restrict__ lo) {
  int idx = blockIdx.x * 256 + threadIdx.x;  // 3*1024*1024
  int l = idx >> 20;
  int h = (idx >> 10) & (HID - 1);
  float w = Ws[idx] * g[(l + 1) * HID + h] * INV_SQRT_BN;
  u16 hb = f2bf_rne(w);
  float hf = __uint_as_float((u32)hb << 16);
  hi[idx] = hb;
  lo[idx] = f2bf_rne(w - hf);
}
__global__ __launch_bounds__(256) void prep_wf_k(const float* __restrict__ Wf,
                                                 const float* __restrict__ g,
                                                 u16* __restrict__ hi) {
  int idx = blockIdx.x * 256 + threadIdx.x;  // 2048*1024
  int o = idx >> 10, k = idx & (HID - 1);
  float w = 0.f;
  if (o < OUTDIM) w = Wf[(size_t)o * HID + k] * g[o] * INV_SQRT_BN;
  hi[idx] = f2bf_rne(w);
}

// ---------------- GEMM: C[m,n] = sum_k A[m,k]*(B0+B1)[n,k] + bias[n] ----
// A [M,K] bf16, B [N,K] bf16 (bt layout), C fp32 [M, ldc], store cols < ncols
template <int SPLIT>
__global__ __launch_bounds__(256, 2) void gemm_bt(const u16* __restrict__ A,
                                                  const u16* __restrict__ B0,
                                                  const u16* __restrict__ B1,
                                                  const float* __restrict__ bias,
                                                  float* __restrict__ C,
                                                  int K, int ldc, int ncols) {
  extern __shared__ char smem[];
  u16* As = (u16*)smem;           // [128][64]
  u16* Bs0 = As + 128 * 64;       // [128][64]
  u16* Bs1 = Bs0 + 128 * 64;      // [128][64] (SPLIT only)

  const int tid = threadIdx.x;
  const int m0 = blockIdx.y * 128;
  const int n0 = blockIdx.x * 128;
  const int lane = tid & 63;
  const int wave = tid >> 6;
  const int wm = (wave & 1) * 64;
  const int wn = (wave >> 1) * 64;
  const int lr = lane & 15;
  const int lk = (lane >> 4) * 8;

  floatx4 acc[4][4];
#pragma unroll
  for (int i = 0; i < 4; ++i)
#pragma unroll
    for (int j = 0; j < 4; ++j) {
      floatx4 z = {0.f, 0.f, 0.f, 0.f};
      acc[i][j] = z;
    }

  const int srow = tid >> 3;          // 0..31
  const int scol = (tid & 7) * 8;     // k element offset
  const u16* ga = A + (size_t)(m0 + srow) * K + scol;
  const u16* gb0 = B0 + (size_t)(n0 + srow) * K + scol;
  const u16* gb1 = SPLIT ? B1 + (size_t)(n0 + srow) * K + scol : (const u16*)nullptr;
  const int ldso = tid * 16;

  for (int k0 = 0; k0 < K; k0 += 64) {
#pragma unroll
    for (int it = 0; it < 4; ++it) {
      g2lds16(ga + (size_t)(it * 32) * K + k0, (char*)As + ldso + it * 4096);
      g2lds16(gb0 + (size_t)(it * 32) * K + k0, (char*)Bs0 + ldso + it * 4096);
      if (SPLIT) g2lds16(gb1 + (size_t)(it * 32) * K + k0, (char*)Bs1 + ldso + it * 4096);
    }
    __syncthreads();
#pragma unroll
    for (int kk = 0; kk < 2; ++kk) {
      const int ko = kk * 32 + lk;
      short8 af[4];
#pragma unroll
      for (int i = 0; i < 4; ++i)
        af[i] = *(const short8*)(As + (wm + i * 16 + lr) * 64 + ko);
#pragma unroll
      for (int j = 0; j < 4; ++j) {
        short8 b0 = *(const short8*)(Bs0 + (wn + j * 16 + lr) * 64 + ko);
#pragma unroll
        for (int i = 0; i < 4; ++i)
          acc[i][j] = __builtin_amdgcn_mfma_f32_16x16x32_bf16(af[i], b0, acc[i][j], 0, 0, 0);
        if (SPLIT) {
          short8 b1 = *(const short8*)(Bs1 + (wn + j * 16 + lr) * 64 + ko);
#pragma unroll
          for (int i = 0; i < 4; ++i)
            acc[i][j] = __builtin_amdgcn_mfma_f32_16x16x32_bf16(af[i], b1, acc[i][j], 0, 0, 0);
        }
      }
    }
    __syncthreads();
  }

  const int rq = (lane >> 4) * 4;
#pragma unroll
  for (int j = 0; j < 4; ++j) {
    int n = n0 + wn + j * 16 + lr;
    if (n < ncols) {
      float bv = bias[n];
#pragma unroll
      for (int i = 0; i < 4; ++i) {
        int mb = m0 + wm + i * 16 + rq;
#pragma unroll
        for (int r = 0; r < 4; ++r)
          C[(size_t)(mb + r) * ldc + n] = acc[i][j][r] + bv;
      }
    }
  }
}

// ---------------- in-place log_softmax over rows of 1944 ----
__global__ __launch_bounds__(256) void logsoftmax_k(float* __restrict__ data) {
  __shared__ float red[8];
  float* p = data + (size_t)blockIdx.x * OUTDIM;
  const int t = threadIdx.x;
  float v[8];
  float mx = -1e30f;
#pragma unroll
  for (int j = 0; j < 8; ++j) {
    int c = t + j * 256;
    v[j] = (c < OUTDIM) ? p[c] : -1e30f;
    mx = fmaxf(mx, v[j]);
  }
#pragma unroll
  for (int o = 32; o > 0; o >>= 1) mx = fmaxf(mx, __shfl_down(mx, o));
  if ((t & 63) == 0) red[t >> 6] = mx;
  __syncthreads();
  mx = fmaxf(fmaxf(red[0], red[1]), fmaxf(red[2], red[3]));
  float s = 0.f;
#pragma unroll
  for (int j = 0; j < 8; ++j) {
    int c = t + j * 256;
    if (c < OUTDIM) s += __expf(v[j] - mx);
  }
#pragma unroll
  for (int o = 32; o > 0; o >>= 1) s += __shfl_down(s, o);
  if ((t & 63) == 0) red[4 + (t >> 6)] = s;
  __syncthreads();
  s = (red[4] + red[5]) + (red[6] + red[7]);
  float lse = mx + __logf(s);
#pragma unroll
  for (int j = 0; j < 8; ++j) {
    int c = t + j * 256;
    if (c < OUTDIM) p[c] = v[j] - lse;
  }
}

extern "C" void kernel_launch(void* const* d_in, const int* in_sizes, int n_in,
                              void* d_out, int out_size, void* d_ws, size_t ws_size,
                              hipStream_t stream) {
  const float* xs = (const float*)d_in[0];
  const float* W0 = (const float*)d_in[1];
  const float* Ws = (const float*)d_in[2];
  const float* taus = (const float*)d_in[3];
  const float* bng = (const float*)d_in[4];
  const float* bnb = (const float*)d_in[5];
  const float* Wf = (const float*)d_in[6];
  const float* fg = (const float*)d_in[7];
  const float* fb = (const float*)d_in[8];
  float* out = (float*)d_out;

  char* p = (char*)d_ws;
  u16* sp0 = (u16*)p;  p += (size_t)MROWS * INPAD * 2;    // 28.7 MB
  u16* sp = (u16*)p;   p += (size_t)MROWS * HID * 2;      // 65.5 MB
  float* wsb = (float*)p; p += (size_t)MROWS * HID * 4;   // 131 MB
  u16* W0hi = (u16*)p; p += (size_t)HID * INPAD * 2;
  u16* W0lo = (u16*)p; p += (size_t)HID * INPAD * 2;
  u16* Whi = (u16*)p;  p += (size_t)3 * HID * HID * 2;
  u16* Wlo = (u16*)p;  p += (size_t)3 * HID * HID * 2;
  u16* Wfhi = (u16*)p; p += (size_t)OUTPAD * HID * 2;

  input_fsq_k<<<(BATCH * INPAD) / 256, 256, 0, stream>>>(xs, sp0);
  prep_w0_k<<<(HID * INPAD) / 256, 256, 0, stream>>>(W0, bng, W0hi, W0lo);
  prep_ws_k<<<(3 * HID * HID) / 256, 256, 0, stream>>>(Ws, bng, Whi, Wlo);
  prep_wf_k<<<(OUTPAD * HID) / 256, 256, 0, stream>>>(Wf, fg, Wfhi);

  // layer 0
  gemm_bt<1><<<dim3(HID / 128, MROWS / 128), 256, 48 * 1024, stream>>>(
      sp0, W0hi, W0lo, bnb, wsb, INPAD, HID, HID);
  lif_k<<<(BATCH * HID) / 256, 256, 0, stream>>>(wsb, taus, sp);
  // layers 1..3
  for (int l = 1; l < 4; ++l) {
    gemm_bt<1><<<dim3(HID / 128, MROWS / 128), 256, 48 * 1024, stream>>>(
        sp, Whi + (size_t)(l - 1) * HID * HID, Wlo + (size_t)(l - 1) * HID * HID,
        bnb + l * HID, wsb, HID, HID, HID);
    lif_k<<<(BATCH * HID) / 256, 256, 0, stream>>>(wsb, taus + l * HID, sp);
  }
  // final projection -> d_out (raw logits), then in-place log_softmax
  gemm_bt<0><<<dim3(OUTPAD / 128, MROWS / 128), 256, 32 * 1024, stream>>>(
      sp, Wfhi, (const u16*)nullptr, fb, out, HID, OUTDIM, OUTDIM);
  logsoftmax_k<<<MROWS, 256, 0, stream>>>(out);
}

// Round 3
// 1074.075 us; speedup vs baseline: 1.4059x; 1.0638x over previous
//
#include <hip/hip_runtime.h>
#include <hip/hip_bf16.h>
#include <cstddef>

typedef unsigned short u16;
typedef unsigned int u32;
typedef short short8 __attribute__((ext_vector_type(8)));
typedef float floatx4 __attribute__((ext_vector_type(4)));

#define T_STEPS 500
#define BATCH 64
#define INDIM 440
#define INPAD 448
#define HID 1024
#define OUTDIM 1944
#define OUTPAD 2048
#define MROWS 32000  // T*B
#define INV_SQRT_BN 0.9999950000374997f  // 1/sqrt(1+1e-5)
#define CH 20        // scan chunk: 500 = 25*20

__device__ __forceinline__ u16 f2bf_rne(float f) {
  u32 u = __float_as_uint(f);
  u32 r = (u + 0x7FFFu + ((u >> 16) & 1u)) >> 16;
  return (u16)r;
}
__device__ __forceinline__ u16 f2bf_exact(float f) {
  return (u16)(__float_as_uint(f) >> 16);
}
__device__ __forceinline__ void g2lds16(const void* g, void* l) {
  __builtin_amdgcn_global_load_lds(
      (const __attribute__((address_space(1))) u32*)g,
      (__attribute__((address_space(3))) u32*)l, 16, 0, 0);
}

// ---------------- input FSQ scan: xs [T,B,440] -> spikes bf16 [T*B, 448] ----
__global__ __launch_bounds__(256) void input_fsq_k(const float* __restrict__ xs,
                                                   u16* __restrict__ sp0) {
  int tid = blockIdx.x * 256 + threadIdx.x;  // 64*448
  int b = tid / INPAD;
  int i = tid - b * INPAD;
  bool act = (i < INDIM);
  const float* src = xs + (size_t)b * INDIM + (act ? i : (INDIM - 1));
  u16* dst = sp0 + (size_t)b * INPAD + i;
  float fact = act ? 1.f : 0.f;
  const int LS = BATCH * INDIM;
  const int SS = BATCH * INPAD;
  float vmem = 0.f;
  float bufA[CH], bufB[CH];
#pragma unroll
  for (int j = 0; j < CH; ++j) bufA[j] = src[(size_t)j * LS];
  for (int it = 0; it < 12; ++it) {
    const int t0 = it * 2 * CH;
#pragma unroll
    for (int j = 0; j < CH; ++j) bufB[j] = src[(size_t)(t0 + CH + j) * LS];
#pragma unroll
    for (int j = 0; j < CH; ++j) {
      vmem += bufA[j] * fact;
      float q = fminf(fmaxf(rintf(vmem), 0.f), 7.f);
      vmem -= q;
      dst[(size_t)(t0 + j) * SS] = f2bf_exact(q);
    }
#pragma unroll
    for (int j = 0; j < CH; ++j) bufA[j] = src[(size_t)(t0 + 2 * CH + j) * LS];
#pragma unroll
    for (int j = 0; j < CH; ++j) {
      vmem += bufB[j] * fact;
      float q = fminf(fmaxf(rintf(vmem), 0.f), 7.f);
      vmem -= q;
      dst[(size_t)(t0 + CH + j) * SS] = f2bf_exact(q);
    }
  }
  const int t0 = 24 * CH;
#pragma unroll
  for (int j = 0; j < CH; ++j) {
    vmem += bufA[j] * fact;
    float q = fminf(fmaxf(rintf(vmem), 0.f), 7.f);
    vmem -= q;
    dst[(size_t)(t0 + j) * SS] = f2bf_exact(q);
  }
}

// ---------------- LIF scan: ws fp32 [T*B, 1024] -> spikes bf16 ----
__global__ __launch_bounds__(256) void lif_k(const float* __restrict__ ws,
                                             const float* __restrict__ taus,
                                             u16* __restrict__ sp) {
  int tid = blockIdx.x * 256 + threadIdx.x;  // 65536 = B*HID
  float tau = taus[tid & (HID - 1)];
  const float* src = ws + tid;
  u16* dst = sp + tid;
  const int S = BATCH * HID;
  float syn = 0.f, vmem = 0.f;
  float bufA[CH], bufB[CH];
#pragma unroll
  for (int j = 0; j < CH; ++j) bufA[j] = src[(size_t)j * S];
  for (int it = 0; it < 12; ++it) {
    const int t0 = it * 2 * CH;
#pragma unroll
    for (int j = 0; j < CH; ++j) bufB[j] = src[(size_t)(t0 + CH + j) * S];
#pragma unroll
    for (int j = 0; j < CH; ++j) {
      syn = fmaf(tau, syn, bufA[j]);
      vmem += syn;
      float q = fminf(fmaxf(rintf(vmem), 0.f), 7.f);
      vmem -= q;
      dst[(size_t)(t0 + j) * S] = f2bf_exact(q);
    }
#pragma unroll
    for (int j = 0; j < CH; ++j) bufA[j] = src[(size_t)(t0 + 2 * CH + j) * S];
#pragma unroll
    for (int j = 0; j < CH; ++j) {
      syn = fmaf(tau, syn, bufB[j]);
      vmem += syn;
      float q = fminf(fmaxf(rintf(vmem), 0.f), 7.f);
      vmem -= q;
      dst[(size_t)(t0 + CH + j) * S] = f2bf_exact(q);
    }
  }
  const int t0 = 24 * CH;
#pragma unroll
  for (int j = 0; j < CH; ++j) {
    syn = fmaf(tau, syn, bufA[j]);
    vmem += syn;
    float q = fminf(fmaxf(rintf(vmem), 0.f), 7.f);
    vmem -= q;
    dst[(size_t)(t0 + j) * S] = f2bf_exact(q);
  }
}

// ---------------- weight prep: fold BN gamma, split to bf16 hi/lo ----
__global__ __launch_bounds__(256) void prep_w0_k(const float* __restrict__ W0,
                                                 const float* __restrict__ g,
                                                 u16* __restrict__ hi, u16* __restrict__ lo) {
  int idx = blockIdx.x * 256 + threadIdx.x;  // 1024*448
  int h = idx / INPAD, k = idx - h * INPAD;
  float w = 0.f;
  if (k < INDIM) w = W0[(size_t)h * INDIM + k] * g[h] * INV_SQRT_BN;
  u16 hb = f2bf_rne(w);
  float hf = __uint_as_float((u32)hb << 16);
  hi[idx] = hb;
  lo[idx] = f2bf_rne(w - hf);
}
__global__ __launch_bounds__(256) void prep_ws_k(const float* __restrict__ Ws,
                                                 const float* __restrict__ g,
                                                 u16* __restrict__ hi, u16* __restrict__ lo) {
  int idx = blockIdx.x * 256 + threadIdx.x;  // 3*1024*1024
  int l = idx >> 20;
  int h = (idx >> 10) & (HID - 1);
  float w = Ws[idx] * g[(l + 1) * HID + h] * INV_SQRT_BN;
  u16 hb = f2bf_rne(w);
  float hf = __uint_as_float((u32)hb << 16);
  hi[idx] = hb;
  lo[idx] = f2bf_rne(w - hf);
}
__global__ __launch_bounds__(256) void prep_wf_k(const float* __restrict__ Wf,
                                                 const float* __restrict__ g,
                                                 u16* __restrict__ hi) {
  int idx = blockIdx.x * 256 + threadIdx.x;  // 2048*1024
  int o = idx >> 10, k = idx & (HID - 1);
  float w = 0.f;
  if (o < OUTDIM) w = Wf[(size_t)o * HID + k] * g[o] * INV_SQRT_BN;
  hi[idx] = f2bf_rne(w);
}

// ---------------- GEMM: C[m,n] = sum_k A[m,k]*(B0+B1)[n,k] + bias[n] ----
// LDS layout uses 16B-chunk XOR swizzle (chunk slot s of row r holds global
// k-chunk s^(r&7)) so 16-rows-per-ds_read_b128 spread across all banks.
// Epilogue stages 32x128 slabs via padded LDS -> full-line float4 stores.
template <int SPLIT>
__global__ __launch_bounds__(256, 2) void gemm_bt(const u16* __restrict__ A,
                                                  const u16* __restrict__ B0,
                                                  const u16* __restrict__ B1,
                                                  const float* __restrict__ bias,
                                                  float* __restrict__ C,
                                                  int K, int ldc, int ncols) {
  extern __shared__ char smem[];
  u16* As = (u16*)smem;           // [128][64] swizzled
  u16* Bs0 = As + 128 * 64;
  u16* Bs1 = Bs0 + 128 * 64;      // SPLIT only

  const int tid = threadIdx.x;
  const int m0 = blockIdx.y * 128;
  const int n0 = blockIdx.x * 128;
  const int lane = tid & 63;
  const int wave = tid >> 6;
  const int wm = (wave & 1) * 64;
  const int wn = (wave >> 1) * 64;
  const int lr = lane & 15;
  const int lq = lane >> 4;      // 0..3

  floatx4 acc[4][4];
#pragma unroll
  for (int i = 0; i < 4; ++i)
#pragma unroll
    for (int j = 0; j < 4; ++j) {
      floatx4 z = {0.f, 0.f, 0.f, 0.f};
      acc[i][j] = z;
    }

  const int srow = tid >> 3;                    // 0..31
  const int sj = (tid & 7) ^ (srow & 7);        // swizzled global k-chunk
  const u16* ga = A + (size_t)(m0 + srow) * K + sj * 8;
  const u16* gb0 = B0 + (size_t)(n0 + srow) * K + sj * 8;
  const u16* gb1 = SPLIT ? B1 + (size_t)(n0 + srow) * K + sj * 8 : (const u16*)nullptr;
  const int ldso = tid * 16;
  const int sw = (lr & 7);                      // row-dependent XOR for reads

  for (int k0 = 0; k0 < K; k0 += 64) {
#pragma unroll
    for (int it = 0; it < 4; ++it) {
      g2lds16(ga + (size_t)(it * 32) * K + k0, (char*)As + ldso + it * 4096);
      g2lds16(gb0 + (size_t)(it * 32) * K + k0, (char*)Bs0 + ldso + it * 4096);
      if (SPLIT) g2lds16(gb1 + (size_t)(it * 32) * K + k0, (char*)Bs1 + ldso + it * 4096);
    }
    __syncthreads();
#pragma unroll
    for (int kk = 0; kk < 2; ++kk) {
      const int jc = kk * 4 + lq;               // global k-chunk 0..7
      const int co = ((jc ^ sw) << 3);          // swizzled element offset
      short8 af[4];
#pragma unroll
      for (int i = 0; i < 4; ++i)
        af[i] = *(const short8*)(As + (wm + i * 16 + lr) * 64 + co);
#pragma unroll
      for (int j = 0; j < 4; ++j) {
        const int bo = (wn + j * 16 + lr) * 64 + co;
        short8 b0 = *(const short8*)(Bs0 + bo);
#pragma unroll
        for (int i = 0; i < 4; ++i)
          acc[i][j] = __builtin_amdgcn_mfma_f32_16x16x32_bf16(af[i], b0, acc[i][j], 0, 0, 0);
        if (SPLIT) {
          short8 b1 = *(const short8*)(Bs1 + bo);
#pragma unroll
          for (int i = 0; i < 4; ++i)
            acc[i][j] = __builtin_amdgcn_mfma_f32_16x16x32_bf16(af[i], b1, acc[i][j], 0, 0, 0);
        }
      }
    }
    __syncthreads();
  }

  // ---- epilogue: 4 slabs of 32 rows x 128 cols via LDS, full-line stores
  float* Es = (float*)smem;        // [32][132] padded
  const int rq = lq * 4;
  const int rbase = (wave & 1) * 16;
#pragma unroll
  for (int i = 0; i < 4; ++i) {
    __syncthreads();
#pragma unroll
    for (int j = 0; j < 4; ++j) {
      int cl = wn + j * 16 + lr;
      int cg = n0 + cl;
      float bv = (cg < ncols) ? bias[cg] : 0.f;
#pragma unroll
      for (int r = 0; r < 4; ++r)
        Es[(rbase + rq + r) * 132 + cl] = acc[i][j][r] + bv;
    }
    __syncthreads();
#pragma unroll
    for (int ps = 0; ps < 4; ++ps) {
      int rl = ps * 8 + (tid >> 5);            // 0..31
      int c4 = (tid & 31) * 4;
      floatx4 v = *(const floatx4*)(Es + rl * 132 + c4);
      int rg = m0 + (rl >> 4) * 64 + i * 16 + (rl & 15);
      int cg = n0 + c4;
      if (cg < ncols)
        *(floatx4*)(C + (size_t)rg * ldc + cg) = v;
    }
  }
}

// ---------------- in-place log_softmax over rows of 1944 ----
__global__ __launch_bounds__(256) void logsoftmax_k(float* __restrict__ data) {
  __shared__ float red[8];
  float* p = data + (size_t)blockIdx.x * OUTDIM;
  const int t = threadIdx.x;
  float v[8];
  float mx = -1e30f;
#pragma unroll
  for (int j = 0; j < 8; ++j) {
    int c = t + j * 256;
    v[j] = (c < OUTDIM) ? p[c] : -1e30f;
    mx = fmaxf(mx, v[j]);
  }
#pragma unroll
  for (int o = 32; o > 0; o >>= 1) mx = fmaxf(mx, __shfl_down(mx, o));
  if ((t & 63) == 0) red[t >> 6] = mx;
  __syncthreads();
  mx = fmaxf(fmaxf(red[0], red[1]), fmaxf(red[2], red[3]));
  float s = 0.f;
#pragma unroll
  for (int j = 0; j < 8; ++j) {
    int c = t + j * 256;
    if (c < OUTDIM) s += __expf(v[j] - mx);
  }
#pragma unroll
  for (int o = 32; o > 0; o >>= 1) s += __shfl_down(s, o);
  if ((t & 63) == 0) red[4 + (t >> 6)] = s;
  __syncthreads();
  s = (red[4] + red[5]) + (red[6] + red[7]);
  float lse = mx + __logf(s);
#pragma unroll
  for (int j = 0; j < 8; ++j) {
    int c = t + j * 256;
    if (c < OUTDIM) p[c] = v[j] - lse;
  }
}

extern "C" void kernel_launch(void* const* d_in, const int* in_sizes, int n_in,
                              void* d_out, int out_size, void* d_ws, size_t ws_size,
                              hipStream_t stream) {
  const float* xs = (const float*)d_in[0];
  const float* W0 = (const float*)d_in[1];
  const float* Ws = (const float*)d_in[2];
  const float* taus = (const float*)d_in[3];
  const float* bng = (const float*)d_in[4];
  const float* bnb = (const float*)d_in[5];
  const float* Wf = (const float*)d_in[6];
  const float* fg = (const float*)d_in[7];
  const float* fb = (const float*)d_in[8];
  float* out = (float*)d_out;

  char* p = (char*)d_ws;
  u16* sp0 = (u16*)p;  p += (size_t)MROWS * INPAD * 2;
  u16* sp = (u16*)p;   p += (size_t)MROWS * HID * 2;
  float* wsb = (float*)p; p += (size_t)MROWS * HID * 4;
  u16* W0hi = (u16*)p; p += (size_t)HID * INPAD * 2;
  u16* W0lo = (u16*)p; p += (size_t)HID * INPAD * 2;
  u16* Whi = (u16*)p;  p += (size_t)3 * HID * HID * 2;
  u16* Wlo = (u16*)p;  p += (size_t)3 * HID * HID * 2;
  u16* Wfhi = (u16*)p; p += (size_t)OUTPAD * HID * 2;

  input_fsq_k<<<(BATCH * INPAD) / 256, 256, 0, stream>>>(xs, sp0);
  prep_w0_k<<<(HID * INPAD) / 256, 256, 0, stream>>>(W0, bng, W0hi, W0lo);
  prep_ws_k<<<(3 * HID * HID) / 256, 256, 0, stream>>>(Ws, bng, Whi, Wlo);
  prep_wf_k<<<(OUTPAD * HID) / 256, 256, 0, stream>>>(Wf, fg, Wfhi);

  // layer 0
  gemm_bt<1><<<dim3(HID / 128, MROWS / 128), 256, 48 * 1024, stream>>>(
      sp0, W0hi, W0lo, bnb, wsb, INPAD, HID, HID);
  lif_k<<<(BATCH * HID) / 256, 256, 0, stream>>>(wsb, taus, sp);
  // layers 1..3
  for (int l = 1; l < 4; ++l) {
    gemm_bt<1><<<dim3(HID / 128, MROWS / 128), 256, 48 * 1024, stream>>>(
        sp, Whi + (size_t)(l - 1) * HID * HID, Wlo + (size_t)(l - 1) * HID * HID,
        bnb + l * HID, wsb, HID, HID, HID);
    lif_k<<<(BATCH * HID) / 256, 256, 0, stream>>>(wsb, taus + l * HID, sp);
  }
  // final projection -> d_out (raw logits), then in-place log_softmax
  gemm_bt<0><<<dim3(OUTPAD / 128, MROWS / 128), 256, 32 * 1024, stream>>>(
      sp, Wfhi, (const u16*)nullptr, fb, out, HID, OUTDIM, OUTDIM);
  logsoftmax_k<<<MROWS, 256, 0, stream>>>(out);
}